// Round 2
// baseline (100.865 us; speedup 1.0000x reference)
//
#include <hip/hip_runtime.h>
#include <limits.h>

#define N_    6
#define C_    80
#define D_    112
#define HF_   16
#define WF_   44
#define NX_   128
#define NY_   128
#define HW_   (HF_ * WF_)          // 704
#define NPIX_ (NX_ * NY_)          // 16384
#define TPX_  4                    // pixels per tile (consecutive w)
#define NTW_  (WF_ / TPX_)         // 11
#define NT_   (HF_ * NTW_)         // 176 tile columns in grid.x
#define NCG_  4                    // channel groups (grid.y)
#define CG_   (C_ / NCG_)          // 20 channels per block
#define PC_   (N_ * TPX_)          // 24 (px,cam) lists per tile
#define CAP_  256                  // max bbox slots (fast path)
#define WPAD_ 25                   // s_wt row stride (coprime w/ 32 banks)
#define FPAD_ 25                   // s_featT row stride (coprime w/ 32 banks)

// ---------------- 3x3 inverse (adjugate) ----------------
__device__ __forceinline__ void inv3(const float* m, float* o) {
    float a = m[0], b = m[1], c = m[2];
    float d = m[3], e = m[4], f = m[5];
    float g = m[6], h = m[7], i = m[8];
    float A  =  (e * i - f * h);
    float Bc = -(d * i - f * g);
    float Cc =  (d * h - e * g);
    float det = a * A + b * Bc + c * Cc;
    float id = 1.0f / det;
    o[0] = A * id;                  o[1] = -(b * i - c * h) * id;   o[2] =  (b * f - c * e) * id;
    o[3] = Bc * id;                 o[4] =  (a * i - c * g) * id;   o[5] = -(a * f - c * d) * id;
    o[6] = Cc * id;                 o[7] = -(a * h - b * g) * id;   o[8] =  (a * e - b * d) * id;
}

__device__ __forceinline__ int voxel_of(float xs, float ys, float dv, const float* sm) {
    const float* ip  = sm;       // invPost
    const float* cmb = sm + 9;   // rots @ inv(intrins)
    float ptx = sm[18], pty = sm[19], ptz = sm[20];
    float trx = sm[21], trY = sm[22], trz = sm[23];
    float p0x = xs - ptx, p0y = ys - pty, p0z = dv - ptz;
    float p1x = ip[0]*p0x + ip[1]*p0y + ip[2]*p0z;
    float p1y = ip[3]*p0x + ip[4]*p0y + ip[5]*p0z;
    float p1z = ip[6]*p0x + ip[7]*p0y + ip[8]*p0z;
    float qx = p1x * p1z, qy = p1y * p1z, qz = p1z;
    float rx = cmb[0]*qx + cmb[1]*qy + cmb[2]*qz + trx;
    float ry = cmb[3]*qx + cmb[4]*qy + cmb[5]*qz + trY;
    float rz = cmb[6]*qx + cmb[7]*qy + cmb[8]*qz + trz;
    const float lox = -50.8f - 0.4f;   // bx - dx/2, f32 fold matches np
    const float loy = -50.8f - 0.4f;
    const float loz = -10.0f;
    int ix = (int)((rx - lox) / 0.8f);   // trunc toward zero == astype(int32)
    int iy = (int)((ry - loy) / 0.8f);
    int iz = (int)((rz - loz) / 20.0f);
    // NZ == 1: valid iz is exactly 0
    bool val = (ix >= 0) && (ix < NX_) && (iy >= 0) && (iy < NY_) && (iz >= 0) && (iz < 1);
    return val ? (ix * NY_ + iy) : -1;
}

// One block per (1x4 pixel tile, channel-group); all 6 cameras; cross-pixel
// voxel merge in LDS. grid = (176, 4): phases 1-3 are replicated per channel
// group (cheap: ~2.7K voxel_of + 24 softmaxes), phase 4's atomic tail and the
// feature staging are split 4x. 176 blocks was <0.7/CU (latency-bound); 704
// blocks gives ~2.75/CU.
__global__ __launch_bounds__(512) void tile_kernel(
    const float* __restrict__ rots, const float* __restrict__ trans,
    const float* __restrict__ intrins, const float* __restrict__ post_rots,
    const float* __restrict__ post_trans,
    const float* __restrict__ img_feat, const float* __restrict__ depth_digit,
    float* __restrict__ outp)
{
    const int tb  = blockIdx.x;
    const int c0  = blockIdx.y * CG_;  // this block's first channel
    const int th  = tb / NTW_;
    const int w0  = (tb - th * NTW_) * TPX_;
    const int hw0 = th * WF_ + w0;     // % 4 == 0 -> float4-aligned rows
    const int tid  = threadIdx.x;
    const int lane = tid & 63;
    const int wave = tid >> 6;

    __shared__ float s_prob[PC_][D_];      // logits -> probs in place (10.75 KB)
    __shared__ short s_vox[PC_][D_];       // 5.25 KB
    __shared__ float s_wt[CAP_][WPAD_];    // 25.6 KB: per-slot weights for 24 lists
    __shared__ float s_featT[CG_][FPAD_];  // 2 KB: feat[c][pc], padded rows
    __shared__ short s_slotvox[CAP_];      // slot -> global vox (-1 = dead)
    __shared__ float s_mat[N_][24];
    __shared__ float s_xs[TPX_];
    __shared__ int   s_bb[4];              // minx, maxx, miny, maxy
    __shared__ int   s_geo[5];             // ix0, iy0, bh, area, fb

    // ---- phase 1: stage inputs (float4 per (cam,row)) + zero accumulators ----
    for (int i = tid; i < N_ * D_; i += 512) {
        int cam = i / D_, d = i - cam * D_;
        float4 v = *(const float4*)(depth_digit + ((size_t)cam * D_ + d) * HW_ + hw0);
        int pc0 = cam * TPX_;
        s_prob[pc0 + 0][d] = v.x;
        s_prob[pc0 + 1][d] = v.y;
        s_prob[pc0 + 2][d] = v.z;
        s_prob[pc0 + 3][d] = v.w;
    }
    for (int i = tid; i < N_ * CG_; i += 512) {
        int cam = i / CG_, c = i - cam * CG_;
        float4 v = *(const float4*)(img_feat + ((size_t)cam * C_ + c0 + c) * HW_ + hw0);
        int pc0 = cam * TPX_;
        s_featT[c][pc0 + 0] = v.x;
        s_featT[c][pc0 + 1] = v.y;
        s_featT[c][pc0 + 2] = v.z;
        s_featT[c][pc0 + 3] = v.w;
    }
    for (int i = tid; i < CAP_ * WPAD_; i += 512) ((float*)s_wt)[i] = 0.0f;
    for (int i = tid; i < CAP_; i += 512) s_slotvox[i] = -1;
    if (tid < 4) s_bb[tid] = (tid == 0 || tid == 2) ? INT_MAX : INT_MIN;
    if (tid >= 8 && tid < 12) s_xs[tid - 8] = (float)((double)(w0 + tid - 8) * (703.0 / 43.0));
    if (tid >= 16 && tid < 16 + N_) {
        int cam = tid - 16;
        float ipv[9], ii[9];
        inv3(post_rots + cam * 9, ipv);
        inv3(intrins + cam * 9, ii);
        const float* ro = rots + cam * 9;
        #pragma unroll
        for (int k = 0; k < 9; ++k) s_mat[cam][k] = ipv[k];
        #pragma unroll
        for (int r = 0; r < 3; ++r)
            #pragma unroll
            for (int c = 0; c < 3; ++c)
                s_mat[cam][9 + r * 3 + c] = ro[r*3+0]*ii[0*3+c] + ro[r*3+1]*ii[1*3+c] + ro[r*3+2]*ii[2*3+c];
        #pragma unroll
        for (int k = 0; k < 3; ++k) { s_mat[cam][18+k] = post_trans[cam*3+k]; s_mat[cam][21+k] = trans[cam*3+k]; }
    }
    __syncthreads();

    // ---- phase 2: softmax (3 lists per wave) + geometry + bbox ----
    #pragma unroll
    for (int j = 0; j < 3; ++j) {
        int pc = wave * 3 + j;
        bool act = lane < 56;
        float l0 = act ? s_prob[pc][lane]      : -INFINITY;
        float l1 = act ? s_prob[pc][lane + 56] : -INFINITY;
        float m = fmaxf(l0, l1);
        #pragma unroll
        for (int o = 32; o > 0; o >>= 1) m = fmaxf(m, __shfl_xor(m, o));
        float e0 = act ? __expf(l0 - m) : 0.0f;
        float e1 = act ? __expf(l1 - m) : 0.0f;
        float s = e0 + e1;
        #pragma unroll
        for (int o = 32; o > 0; o >>= 1) s += __shfl_xor(s, o);
        float inv = 1.0f / s;
        if (act) { s_prob[pc][lane] = e0 * inv; s_prob[pc][lane + 56] = e1 * inv; }
    }
    {
        float ys = (float)th * 17.0f;   // np.linspace(0,255,16)
        int mnx = INT_MAX, mxx = INT_MIN, mny = INT_MAX, mxy = INT_MIN;
        for (int i = tid; i < PC_ * D_; i += 512) {
            int pc = i / D_, d = i - pc * D_;
            int cam = pc >> 2, px = pc & 3;
            int v = voxel_of(s_xs[px], ys, 2.0f + 0.5f * (float)d, s_mat[cam]);
            s_vox[pc][d] = (short)v;
            if (v >= 0) {
                int ix = v >> 7, iy = v & 127;
                mnx = min(mnx, ix); mxx = max(mxx, ix);
                mny = min(mny, iy); mxy = max(mxy, iy);
            }
        }
        if (mxx >= 0) {
            atomicMin(&s_bb[0], mnx); atomicMax(&s_bb[1], mxx);
            atomicMin(&s_bb[2], mny); atomicMax(&s_bb[3], mxy);
        }
    }
    __syncthreads();

    if (tid == 0) {
        if (s_bb[1] < s_bb[0]) { s_geo[3] = 0; s_geo[4] = 0; }
        else {
            int bw = s_bb[1] - s_bb[0] + 1;
            int bh = s_bb[3] - s_bb[2] + 1;
            int area = bw * bh;
            s_geo[0] = s_bb[0]; s_geo[1] = s_bb[2]; s_geo[2] = bh;
            s_geo[3] = area; s_geo[4] = (area > CAP_) ? 1 : 0;
        }
    }
    __syncthreads();

    int area = s_geo[3];
    int fb   = s_geo[4];

    if (area > 0 && !fb) {
        // ---- phase 3: insert runs into bbox mini-plane (LDS atomics) ----
        int ix0 = s_geo[0], iy0 = s_geo[1], bh = s_geo[2];
        for (int i = tid; i < PC_ * D_; i += 512) {
            int pc = i / D_, d = i - pc * D_;
            int v = s_vox[pc][d];
            if (v >= 0) {
                int slot = ((v >> 7) - ix0) * bh + ((v & 127) - iy0);
                atomicAdd(&s_wt[slot][pc], s_prob[pc][d]);
                s_slotvox[slot] = (short)v;    // benign race, same value
            }
        }
        __syncthreads();

        // ---- phase 4: one global atomic per (live slot, channel in group) ----
        int live = area * CG_;
        for (int k = tid; k < live; k += 512) {
            int slot = k / CG_;
            int c    = k - slot * CG_;
            int v = s_slotvox[slot];
            if (v >= 0) {
                float val = 0.0f;
                #pragma unroll
                for (int j = 0; j < PC_; ++j)
                    val = fmaf(s_wt[slot][j], s_featT[c][j], val);
                atomicAdd(&outp[(size_t)(c0 + c) * NPIX_ + v], val);
            }
        }
    } else if (fb) {
        // ---- fallback (generic cameras, bbox too large): per-bin atomics ----
        for (int k = tid; k < PC_ * D_ * CG_; k += 512) {
            int pcd = k / CG_, c = k - pcd * CG_;
            int pc = pcd / D_, d = pcd - pc * D_;
            int v = s_vox[pc][d];
            if (v >= 0)
                atomicAdd(&outp[(size_t)(c0 + c) * NPIX_ + v], s_prob[pc][d] * s_featT[c][pc]);
        }
    }
}

extern "C" void kernel_launch(void* const* d_in, const int* in_sizes, int n_in,
                              void* d_out, int out_size, void* d_ws, size_t ws_size,
                              hipStream_t stream) {
    const float* rots        = (const float*)d_in[1];
    const float* trans       = (const float*)d_in[2];
    const float* intrins     = (const float*)d_in[3];
    const float* post_rots   = (const float*)d_in[4];
    const float* post_trans  = (const float*)d_in[5];
    const float* img_feat    = (const float*)d_in[6];
    const float* depth_digit = (const float*)d_in[7];
    float* outp = (float*)d_out;

    // Zero only the logical C*NX*NY output (round-1 A/B proved out_size is
    // already the logical 5.24 MB; the 268 MB fills in the trace are the
    // harness's own re-poison, outside our control).
    size_t logical_bytes = (size_t)C_ * NPIX_ * sizeof(float);
    size_t alloc_bytes   = (size_t)out_size * sizeof(float);
    (void)hipMemsetAsync(outp, 0, logical_bytes < alloc_bytes ? logical_bytes : alloc_bytes, stream);
    dim3 grid(NT_, NCG_);
    tile_kernel<<<grid, 512, 0, stream>>>(rots, trans, intrins, post_rots, post_trans,
                                          img_feat, depth_digit, outp);
}

// Round 3
// 90.197 us; speedup vs baseline: 1.1183x; 1.1183x over previous
//
#include <hip/hip_runtime.h>
#include <limits.h>

#define N_    6
#define C_    80
#define D_    112
#define HF_   16
#define WF_   44
#define NX_   128
#define NY_   128
#define HW_   (HF_ * WF_)          // 704
#define NPIX_ (NX_ * NY_)          // 16384
#define TPX_  4                    // pixels per tile (consecutive w)
#define NTW_  (WF_ / TPX_)         // 11
#define NT_   (HF_ * NTW_)         // 176 blocks
#define PC_   (N_ * TPX_)          // 24 (px,cam) lists per tile
#define CAP_  256                  // max bbox slots (fast path)
#define WPAD_ 25                   // s_wt row stride (coprime w/ 32 banks)
#define FPAD_ 25                   // s_featT row stride (coprime w/ 32 banks)

// ---------------- 3x3 inverse (adjugate) ----------------
__device__ __forceinline__ void inv3(const float* m, float* o) {
    float a = m[0], b = m[1], c = m[2];
    float d = m[3], e = m[4], f = m[5];
    float g = m[6], h = m[7], i = m[8];
    float A  =  (e * i - f * h);
    float Bc = -(d * i - f * g);
    float Cc =  (d * h - e * g);
    float det = a * A + b * Bc + c * Cc;
    float id = 1.0f / det;
    o[0] = A * id;                  o[1] = -(b * i - c * h) * id;   o[2] =  (b * f - c * e) * id;
    o[3] = Bc * id;                 o[4] =  (a * i - c * g) * id;   o[5] = -(a * f - c * d) * id;
    o[6] = Cc * id;                 o[7] = -(a * h - b * g) * id;   o[8] =  (a * e - b * d) * id;
}

// mm is a 24-float REGISTER array (hoisted per (pc) list, not re-read from LDS)
__device__ __forceinline__ int voxel_of(float xs, float ys, float dv, const float* mm) {
    const float* ip  = mm;       // invPost
    const float* cmb = mm + 9;   // rots @ inv(intrins)
    float ptx = mm[18], pty = mm[19], ptz = mm[20];
    float trx = mm[21], trY = mm[22], trz = mm[23];
    float p0x = xs - ptx, p0y = ys - pty, p0z = dv - ptz;
    float p1x = ip[0]*p0x + ip[1]*p0y + ip[2]*p0z;
    float p1y = ip[3]*p0x + ip[4]*p0y + ip[5]*p0z;
    float p1z = ip[6]*p0x + ip[7]*p0y + ip[8]*p0z;
    float qx = p1x * p1z, qy = p1y * p1z, qz = p1z;
    float rx = cmb[0]*qx + cmb[1]*qy + cmb[2]*qz + trx;
    float ry = cmb[3]*qx + cmb[4]*qy + cmb[5]*qz + trY;
    float rz = cmb[6]*qx + cmb[7]*qy + cmb[8]*qz + trz;
    const float lox = -50.8f - 0.4f;   // bx - dx/2, f32 fold matches np
    const float loy = -50.8f - 0.4f;
    const float loz = -10.0f;
    int ix = (int)((rx - lox) / 0.8f);   // trunc toward zero == astype(int32)
    int iy = (int)((ry - loy) / 0.8f);
    int iz = (int)((rz - loz) / 20.0f);
    // NZ == 1: valid iz is exactly 0
    bool val = (ix >= 0) && (ix < NX_) && (iy >= 0) && (iy < NY_) && (iz >= 0) && (iz < 1);
    return val ? (ix * NY_ + iy) : -1;
}

// One block per 1x4 pixel tile; all 6 cameras; cross-pixel voxel merge in LDS.
// Round-2 lesson: grid.y channel split regressed (phases 1-3 dominate, kernel
// is latency-bound on the per-block chain) -> single grid, shorten the chain:
//  - wave-major (pc,d) mapping: camera matrix hoisted to registers, no divs
//  - slot-major phase 4: s_wt row broadcast hoisted, dead slots skipped
//    wave-uniformly, no div by 80
__global__ __launch_bounds__(512) void tile_kernel(
    const float* __restrict__ rots, const float* __restrict__ trans,
    const float* __restrict__ intrins, const float* __restrict__ post_rots,
    const float* __restrict__ post_trans,
    const float* __restrict__ img_feat, const float* __restrict__ depth_digit,
    float* __restrict__ outp)
{
    const int tb  = blockIdx.x;
    const int th  = tb / NTW_;
    const int w0  = (tb - th * NTW_) * TPX_;
    const int hw0 = th * WF_ + w0;     // % 4 == 0 -> float4-aligned rows
    const int tid  = threadIdx.x;
    const int lane = tid & 63;
    const int wave = tid >> 6;

    __shared__ float s_prob[PC_][D_];      // logits -> probs in place (10.75 KB)
    __shared__ short s_vox[PC_][D_];       // 5.25 KB
    __shared__ float s_wt[CAP_][WPAD_];    // 25.6 KB: per-slot weights for 24 lists
    __shared__ float s_featT[C_][FPAD_];   // 8 KB: feat[c][pc], padded rows
    __shared__ short s_slotvox[CAP_];      // slot -> global vox (-1 = dead)
    __shared__ float s_mat[N_][24];
    __shared__ float s_xs[TPX_];
    __shared__ int   s_bb[4];              // minx, maxx, miny, maxy
    __shared__ int   s_geo[5];             // ix0, iy0, bh, area, fb

    // ---- phase 1: stage inputs (float4 per (cam,row)) + zero accumulators ----
    for (int i = tid; i < N_ * D_; i += 512) {
        int cam = i / D_, d = i - cam * D_;
        float4 v = *(const float4*)(depth_digit + ((size_t)cam * D_ + d) * HW_ + hw0);
        int pc0 = cam * TPX_;
        s_prob[pc0 + 0][d] = v.x;
        s_prob[pc0 + 1][d] = v.y;
        s_prob[pc0 + 2][d] = v.z;
        s_prob[pc0 + 3][d] = v.w;
    }
    for (int i = tid; i < N_ * C_; i += 512) {
        int cam = i / C_, c = i - cam * C_;
        float4 v = *(const float4*)(img_feat + ((size_t)cam * C_ + c) * HW_ + hw0);
        int pc0 = cam * TPX_;
        s_featT[c][pc0 + 0] = v.x;
        s_featT[c][pc0 + 1] = v.y;
        s_featT[c][pc0 + 2] = v.z;
        s_featT[c][pc0 + 3] = v.w;
    }
    for (int i = tid; i < (CAP_ * WPAD_) / 4; i += 512)
        ((float4*)s_wt)[i] = make_float4(0.f, 0.f, 0.f, 0.f);
    for (int i = tid; i < CAP_ / 2; i += 512) ((int*)s_slotvox)[i] = -1; // 2x short -1
    if (tid < 4) s_bb[tid] = (tid == 0 || tid == 2) ? INT_MAX : INT_MIN;
    if (tid >= 8 && tid < 12) s_xs[tid - 8] = (float)((double)(w0 + tid - 8) * (703.0 / 43.0));
    if (tid >= 16 && tid < 16 + N_) {
        int cam = tid - 16;
        float ipv[9], ii[9];
        inv3(post_rots + cam * 9, ipv);
        inv3(intrins + cam * 9, ii);
        const float* ro = rots + cam * 9;
        #pragma unroll
        for (int k = 0; k < 9; ++k) s_mat[cam][k] = ipv[k];
        #pragma unroll
        for (int r = 0; r < 3; ++r)
            #pragma unroll
            for (int c = 0; c < 3; ++c)
                s_mat[cam][9 + r * 3 + c] = ro[r*3+0]*ii[0*3+c] + ro[r*3+1]*ii[1*3+c] + ro[r*3+2]*ii[2*3+c];
        #pragma unroll
        for (int k = 0; k < 3; ++k) { s_mat[cam][18+k] = post_trans[cam*3+k]; s_mat[cam][21+k] = trans[cam*3+k]; }
    }
    __syncthreads();

    // ---- phase 2: softmax (3 lists per wave) + geometry + bbox ----
    #pragma unroll
    for (int j = 0; j < 3; ++j) {
        int pc = wave * 3 + j;
        bool act = lane < 56;
        float l0 = act ? s_prob[pc][lane]      : -INFINITY;
        float l1 = act ? s_prob[pc][lane + 56] : -INFINITY;
        float m = fmaxf(l0, l1);
        #pragma unroll
        for (int o = 32; o > 0; o >>= 1) m = fmaxf(m, __shfl_xor(m, o));
        float e0 = act ? __expf(l0 - m) : 0.0f;
        float e1 = act ? __expf(l1 - m) : 0.0f;
        float s = e0 + e1;
        #pragma unroll
        for (int o = 32; o > 0; o >>= 1) s += __shfl_xor(s, o);
        float inv = 1.0f / s;
        if (act) { s_prob[pc][lane] = e0 * inv; s_prob[pc][lane + 56] = e1 * inv; }
    }
    {
        // wave-major geometry: pc fixed per j -> camera matrix in registers,
        // d = lane (+64), no integer div in the loop
        float ys = (float)th * 17.0f;   // np.linspace(0,255,16)
        int mnx = INT_MAX, mxx = INT_MIN, mny = INT_MAX, mxy = INT_MIN;
        #pragma unroll
        for (int j = 0; j < 3; ++j) {
            int pc  = wave * 3 + j;
            int cam = pc >> 2, px = pc & 3;
            float mm[24];
            #pragma unroll
            for (int k = 0; k < 24; ++k) mm[k] = s_mat[cam][k];
            float xs = s_xs[px];
            #pragma unroll
            for (int t = 0; t < 2; ++t) {
                int d = lane + t * 64;
                if (d < D_) {
                    int v = voxel_of(xs, ys, 2.0f + 0.5f * (float)d, mm);
                    s_vox[pc][d] = (short)v;
                    if (v >= 0) {
                        int ix = v >> 7, iy = v & 127;
                        mnx = min(mnx, ix); mxx = max(mxx, ix);
                        mny = min(mny, iy); mxy = max(mxy, iy);
                    }
                }
            }
        }
        if (mxx >= 0) {
            atomicMin(&s_bb[0], mnx); atomicMax(&s_bb[1], mxx);
            atomicMin(&s_bb[2], mny); atomicMax(&s_bb[3], mxy);
        }
    }
    __syncthreads();

    if (tid == 0) {
        if (s_bb[1] < s_bb[0]) { s_geo[3] = 0; s_geo[4] = 0; }
        else {
            int bw = s_bb[1] - s_bb[0] + 1;
            int bh = s_bb[3] - s_bb[2] + 1;
            int area = bw * bh;
            s_geo[0] = s_bb[0]; s_geo[1] = s_bb[2]; s_geo[2] = bh;
            s_geo[3] = area; s_geo[4] = (area > CAP_) ? 1 : 0;
        }
    }
    __syncthreads();

    int area = s_geo[3];
    int fb   = s_geo[4];

    if (area > 0 && !fb) {
        // ---- phase 3: insert runs into bbox mini-plane (LDS atomics) ----
        int ix0 = s_geo[0], iy0 = s_geo[1], bh = s_geo[2];
        #pragma unroll
        for (int j = 0; j < 3; ++j) {
            int pc = wave * 3 + j;
            #pragma unroll
            for (int t = 0; t < 2; ++t) {
                int d = lane + t * 64;
                if (d < D_) {
                    int v = s_vox[pc][d];
                    if (v >= 0) {
                        int slot = ((v >> 7) - ix0) * bh + ((v & 127) - iy0);
                        atomicAdd(&s_wt[slot][pc], s_prob[pc][d]);
                        s_slotvox[slot] = (short)v;    // benign race, same value
                    }
                }
            }
        }
        __syncthreads();

        // ---- phase 4: slot-major; one global atomic per (live slot, channel) ----
        for (int slot = wave; slot < area; slot += 8) {
            int v = s_slotvox[slot];
            if (v < 0) continue;               // wave-uniform dead-slot skip
            float wt[PC_];
            #pragma unroll
            for (int j = 0; j < PC_; ++j) wt[j] = s_wt[slot][j];  // broadcast, hoisted
            #pragma unroll
            for (int t = 0; t < 2; ++t) {
                int c = lane + t * 64;
                if (c < C_) {
                    float val = 0.0f;
                    #pragma unroll
                    for (int j = 0; j < PC_; ++j)
                        val = fmaf(wt[j], s_featT[c][j], val);
                    atomicAdd(&outp[(size_t)c * NPIX_ + v], val);
                }
            }
        }
    } else if (fb) {
        // ---- fallback (generic cameras, bbox too large): per-bin atomics ----
        for (int k = tid; k < PC_ * D_ * C_; k += 512) {
            int pcd = k / C_, c = k - pcd * C_;
            int pc = pcd / D_, d = pcd - pc * D_;
            int v = s_vox[pc][d];
            if (v >= 0)
                atomicAdd(&outp[(size_t)c * NPIX_ + v], s_prob[pc][d] * s_featT[c][pc]);
        }
    }
}

extern "C" void kernel_launch(void* const* d_in, const int* in_sizes, int n_in,
                              void* d_out, int out_size, void* d_ws, size_t ws_size,
                              hipStream_t stream) {
    const float* rots        = (const float*)d_in[1];
    const float* trans       = (const float*)d_in[2];
    const float* intrins     = (const float*)d_in[3];
    const float* post_rots   = (const float*)d_in[4];
    const float* post_trans  = (const float*)d_in[5];
    const float* img_feat    = (const float*)d_in[6];
    const float* depth_digit = (const float*)d_in[7];
    float* outp = (float*)d_out;

    // Zero only the logical C*NX*NY output. (Round-1 A/B: the 268 MB fills in
    // the trace are the harness's own re-poison, not ours.)
    size_t logical_bytes = (size_t)C_ * NPIX_ * sizeof(float);
    size_t alloc_bytes   = (size_t)out_size * sizeof(float);
    (void)hipMemsetAsync(outp, 0, logical_bytes < alloc_bytes ? logical_bytes : alloc_bytes, stream);
    tile_kernel<<<NT_, 512, 0, stream>>>(rots, trans, intrins, post_rots, post_trans,
                                         img_feat, depth_digit, outp);
}